// Round 4
// baseline (350.335 us; speedup 1.0000x reference)
//
#include <hip/hip_runtime.h>
#include <hip/hip_fp16.h>
#include <math.h>

#define B_ 128
#define C_ 10
#define R_ 8192
#define I_ 8
#define O_ 16

typedef __attribute__((ext_vector_type(8))) _Float16 half8;
typedef __attribute__((ext_vector_type(16))) float f32x16;

#define XROW 512           // uints per x r-row: 128 b * 4
#define WROW 64            // uints per W row: 16 o * 4
#define WZERO 80           // zero-row index (block-diagonal A trick)
#define SBO (C_ * B_ * O_) // 20480
#define NRED 32            // slots summed per reduce1 block (1024/32 groups)

__device__ __forceinline__ unsigned pk2(float a, float b) {
    __half2 h = __floats2half2_rn(a, b);
    return *(unsigned*)&h;
}

__device__ __forceinline__ float dot8lo(const f32x16& u, const float4& va, const float4& vb) {
    return u[0] * va.x + u[1] * va.y + u[2] * va.z + u[3] * va.w
         + u[4] * vb.x + u[5] * vb.y + u[6] * vb.z + u[7] * vb.w;
}
__device__ __forceinline__ float dot8hi(const f32x16& u, const float4& va, const float4& vb) {
    return u[8] * va.x + u[9] * va.y + u[10] * va.z + u[11] * va.w
         + u[12] * vb.x + u[13] * vb.y + u[14] * vb.z + u[15] * vb.w;
}

// ---------------------------------------------------------------------------
// fused_iter: one routing iteration. grid 1024 (r-tiles of 8), block 256.
// Diagnosis r3: mode0 == mode1 duration -> LATENCY-bound (4 waves/SIMD, long
// ds_read->MFMA->dot->shfl->exp chain), and the 1.57M bank conflicts are the
// x-stage WRITES (16-bank aliasing), not the MFMA reads.
// Fixes this round:
//  - c-loop stepped by 2: TWO independent MFMA/dot/exp chains per iteration
//    (ILP attacks the latency-bound regime; c-loop stays rolled - r2 spill).
//  - acc folded to 8-wide: acc8[j] += c0*u[j] + c1*u[j+8] (halves acc VGPRs).
//  - x-stage XOR swizzle (dword ^= rr<<2, read-side compensated): kills the
//    8-way write conflict.
// Output: part[slot=blockIdx.x][c][b][o] fp16 partial s sums.
// ---------------------------------------------------------------------------
__global__ __launch_bounds__(256, 4) void fused_iter(const float* __restrict__ x,
                                                     const float* __restrict__ w,
                                                     const float* __restrict__ vsum,  // [C][B][16]
                                                     __half* __restrict__ part,
                                                     int mode) {
    __shared__ unsigned xls[8 * XROW];          // 16 KB
    __shared__ unsigned wls[(80 + 1) * WROW];   // 20.25 KB

    const int tid = threadIdx.x;
    const int wave = tid >> 6;
    const int lane = tid & 63;
    const int n = lane & 31;
    const int g = lane >> 5;            // k-half / o-half selector
    const int rp_m = (lane & 31) >> 4;  // r' of this lane's A row
    const int o_m = lane & 15;          // o of this lane's A row
    const int b = wave * 32 + n;        // global batch 0..127
    const int r0 = blockIdx.x * 8;

    // ---- stage x tile fp16: xls[r][ (b*4)^(r<<2) ], once (XOR-swizzled) ----
#pragma unroll
    for (int k = 0; k < 8; ++k) {
        const int f = k * 256 + tid;            // 0..2047
        const int bb = f >> 4;
        const int rr = (f >> 1) & 7;
        const int q = f & 1;
        const float4 v = *(const float4*)(x + ((size_t)bb * R_ + r0 + rr) * 8 + q * 4);
        // swizzle: XOR dword index by rr<<2 (bits 2-4) -> wave spreads 32 banks
        *(uint2*)(xls + rr * XROW + (((bb * 4 + q * 2) ^ (rr << 2)))) =
            make_uint2(pk2(v.x, v.y), pk2(v.z, v.w));
    }
    // ---- stage W for ALL c fp16: wls[c*8+r][o][4 b32], once ----
#pragma unroll
    for (int k = 0; k < 5; ++k) {
        const int id = k * 256 + tid;           // 0..1279 = (c, r, o)
        const int o = id & 15;
        const int r = (id >> 4) & 7;
        const int c = id >> 7;
        const float* wp = w + ((size_t)(c * R_ + r0 + r) * 8) * 16 + o;
        const float f0 = wp[0],  f1 = wp[16],  f2 = wp[32],  f3 = wp[48];
        const float f4 = wp[64], f5 = wp[80],  f6 = wp[96],  f7 = wp[112];
        *(uint4*)(wls + (c * 8 + r) * WROW + o * 4) =
            make_uint4(pk2(f0, f1), pk2(f2, f3), pk2(f4, f5), pk2(f6, f7));
    }
    if (tid < WROW) wls[WZERO * WROW + tid] = 0u;
    __syncthreads();

    const int act = (g == rp_m);

    // hoisted x fragments (c-invariant, 16 VGPRs); read compensates the swizzle
    half8 xbr[4];
#pragma unroll
    for (int rp = 0; rp < 4; ++rp) {
        const int row = 2 * rp + g;
        xbr[rp] = *(const half8*)(xls + row * XROW + ((b * 4) ^ (row << 2)));
    }

    // hoisted zero accumulator: MFMA C operand (D != C), no per-use init
    f32x16 zero16;
#pragma unroll
    for (int j = 0; j < 16; ++j) zero16[j] = 0.f;

    if (mode) {
        // ================= mode 1: softmax-weighted =================
        // ---- phase 2: denominators d[r] = sum_c exp(p[c,r]), dual c-chains ----
        float dinv[4];
        {
            float dacc[4] = {0.f, 0.f, 0.f, 0.f};
#pragma unroll 1
            for (int c = 0; c < C_; c += 2) {
                const float4* vpA = (const float4*)(vsum + ((size_t)c * B_ + b) * O_ + 4 * g);
                const float4* vpB = (const float4*)(vsum + ((size_t)(c + 1) * B_ + b) * O_ + 4 * g);
                const float4 vaA = vpA[0], vbA = vpA[2];
                const float4 vaB = vpB[0], vbB = vpB[2];
#pragma unroll
                for (int rp = 0; rp < 4; ++rp) {
                    const int woffA = act ? ((c * 8 + 2 * rp + g) * WROW + o_m * 4)
                                          : (WZERO * WROW);
                    const int woffB = act ? (((c + 1) * 8 + 2 * rp + g) * WROW + o_m * 4)
                                          : (WZERO * WROW);
                    const half8 aA = *(const half8*)(wls + woffA);
                    const half8 aB = *(const half8*)(wls + woffB);
                    const f32x16 uA = __builtin_amdgcn_mfma_f32_32x32x16_f16(aA, xbr[rp], zero16, 0, 0, 0);
                    const f32x16 uB = __builtin_amdgcn_mfma_f32_32x32x16_f16(aB, xbr[rp], zero16, 0, 0, 0);
                    const float pA0 = dot8lo(uA, vaA, vbA), pA1 = dot8hi(uA, vaA, vbA);
                    const float pB0 = dot8lo(uB, vaB, vbB), pB1 = dot8hi(uB, vaB, vbB);
                    const float recvA = __shfl_xor(g ? pA0 : pA1, 32);
                    const float recvB = __shfl_xor(g ? pB0 : pB1, 32);
                    const float pgA = (g ? pA1 : pA0) + recvA;
                    const float pgB = (g ? pB1 : pB0) + recvB;
                    dacc[rp] += __expf(pgA) + __expf(pgB);
                }
            }
#pragma unroll
            for (int rp = 0; rp < 4; ++rp) dinv[rp] = 1.0f / dacc[rp];
        }

        // ---- phase 3: weighted accumulation, dual c-chains, 8-wide acc ----
#pragma unroll 1
        for (int c = 0; c < C_; c += 2) {
            const float4* vpA = (const float4*)(vsum + ((size_t)c * B_ + b) * O_ + 4 * g);
            const float4* vpB = (const float4*)(vsum + ((size_t)(c + 1) * B_ + b) * O_ + 4 * g);
            const float4 vaA = vpA[0], vbA = vpA[2];
            const float4 vaB = vpB[0], vbB = vpB[2];
            float accA[8], accB[8];
#pragma unroll
            for (int j = 0; j < 8; ++j) { accA[j] = 0.f; accB[j] = 0.f; }
#pragma unroll
            for (int rp = 0; rp < 4; ++rp) {
                const int woffA = act ? ((c * 8 + 2 * rp + g) * WROW + o_m * 4)
                                      : (WZERO * WROW);
                const int woffB = act ? (((c + 1) * 8 + 2 * rp + g) * WROW + o_m * 4)
                                      : (WZERO * WROW);
                const half8 aA = *(const half8*)(wls + woffA);
                const half8 aB = *(const half8*)(wls + woffB);
                const f32x16 uA = __builtin_amdgcn_mfma_f32_32x32x16_f16(aA, xbr[rp], zero16, 0, 0, 0);
                const f32x16 uB = __builtin_amdgcn_mfma_f32_32x32x16_f16(aB, xbr[rp], zero16, 0, 0, 0);
                const float pA0 = dot8lo(uA, vaA, vbA), pA1 = dot8hi(uA, vaA, vbA);
                const float pB0 = dot8lo(uB, vaB, vbB), pB1 = dot8hi(uB, vaB, vbB);
                const float recvA = __shfl_xor(g ? pA0 : pA1, 32);
                const float recvB = __shfl_xor(g ? pB0 : pB1, 32);
                const float pgA = (g ? pA1 : pA0) + recvA;
                const float pgB = (g ? pB1 : pB0) + recvB;
                const float wA = __expf(pgA) * dinv[rp];     // weight for r = 2rp+g
                const float wB = __expf(pgB) * dinv[rp];
                const float wAo = __shfl_xor(wA, 32);        // partner's weight
                const float wBo = __shfl_xor(wB, 32);
                const float cA0 = g ? wAo : wA, cA1 = g ? wA : wAo;
                const float cB0 = g ? wBo : wB, cB1 = g ? wB : wBo;
#pragma unroll
                for (int j = 0; j < 8; ++j) {
                    accA[j] += cA0 * uA[j] + cA1 * uA[j + 8];
                    accB[j] += cB0 * uB[j] + cB1 * uB[j + 8];
                }
            }
            __half* ppA = part + (((size_t)blockIdx.x * C_ + c) * B_ + b) * O_;
            *(uint2*)(ppA + 4 * g)     = make_uint2(pk2(accA[0], accA[1]), pk2(accA[2], accA[3]));
            *(uint2*)(ppA + 8 + 4 * g) = make_uint2(pk2(accA[4], accA[5]), pk2(accA[6], accA[7]));
            __half* ppB = part + (((size_t)blockIdx.x * C_ + (c + 1)) * B_ + b) * O_;
            *(uint2*)(ppB + 4 * g)     = make_uint2(pk2(accB[0], accB[1]), pk2(accB[2], accB[3]));
            *(uint2*)(ppB + 8 + 4 * g) = make_uint2(pk2(accB[4], accB[5]), pk2(accB[6], accB[7]));
        }
    } else {
        // ================= mode 0: uniform weights 0.1, dual chains =================
#pragma unroll 1
        for (int c = 0; c < C_; c += 2) {
            f32x16 accA = zero16, accB = zero16;
#pragma unroll
            for (int rp = 0; rp < 4; ++rp) {
                const int woffA = act ? ((c * 8 + 2 * rp + g) * WROW + o_m * 4)
                                      : (WZERO * WROW);
                const int woffB = act ? (((c + 1) * 8 + 2 * rp + g) * WROW + o_m * 4)
                                      : (WZERO * WROW);
                const half8 aA = *(const half8*)(wls + woffA);
                const half8 aB = *(const half8*)(wls + woffB);
                accA = __builtin_amdgcn_mfma_f32_32x32x16_f16(aA, xbr[rp], accA, 0, 0, 0);
                accB = __builtin_amdgcn_mfma_f32_32x32x16_f16(aB, xbr[rp], accB, 0, 0, 0);
            }
            __half* ppA = part + (((size_t)blockIdx.x * C_ + c) * B_ + b) * O_;
            *(uint2*)(ppA + 4 * g)     = make_uint2(pk2((accA[0] + accA[8]) * 0.1f, (accA[1] + accA[9]) * 0.1f),
                                                    pk2((accA[2] + accA[10]) * 0.1f, (accA[3] + accA[11]) * 0.1f));
            *(uint2*)(ppA + 8 + 4 * g) = make_uint2(pk2((accA[4] + accA[12]) * 0.1f, (accA[5] + accA[13]) * 0.1f),
                                                    pk2((accA[6] + accA[14]) * 0.1f, (accA[7] + accA[15]) * 0.1f));
            __half* ppB = part + (((size_t)blockIdx.x * C_ + (c + 1)) * B_ + b) * O_;
            *(uint2*)(ppB + 4 * g)     = make_uint2(pk2((accB[0] + accB[8]) * 0.1f, (accB[1] + accB[9]) * 0.1f),
                                                    pk2((accB[2] + accB[10]) * 0.1f, (accB[3] + accB[11]) * 0.1f));
            *(uint2*)(ppB + 8 + 4 * g) = make_uint2(pk2((accB[4] + accB[12]) * 0.1f, (accB[5] + accB[13]) * 0.1f),
                                                    pk2((accB[6] + accB[14]) * 0.1f, (accB[7] + accB[15]) * 0.1f));
        }
    }
}

// ---------------------------------------------------------------------------
// reduce1: part2[by][..] = sum of NRED slot-partials. grid (10, 1024/NRED)=
// (10,32) -> 320 blocks (r3's 160 blocks = 640 waves couldn't fill HBM).
// Each thread owns 8 consecutive halfs, uint4 loads (16B/lane, coalesced).
// ---------------------------------------------------------------------------
__global__ __launch_bounds__(256) void reduce1(const __half* __restrict__ part,
                                               float* __restrict__ part2) {
    const int t8 = blockIdx.x * 256 + threadIdx.x;      // 0..2559
    const __half* p = part + (size_t)(blockIdx.y * NRED) * SBO + (size_t)t8 * 8;
    float s0 = 0.f, s1 = 0.f, s2 = 0.f, s3 = 0.f;
    float s4 = 0.f, s5 = 0.f, s6 = 0.f, s7 = 0.f;
#pragma unroll 8
    for (int s = 0; s < NRED; ++s) {
        const uint4 v = *(const uint4*)(p + (size_t)s * SBO);
        const float2 f0 = __half22float2(*(const __half2*)&v.x);
        const float2 f1 = __half22float2(*(const __half2*)&v.y);
        const float2 f2 = __half22float2(*(const __half2*)&v.z);
        const float2 f3 = __half22float2(*(const __half2*)&v.w);
        s0 += f0.x; s1 += f0.y; s2 += f1.x; s3 += f1.y;
        s4 += f2.x; s5 += f2.y; s6 += f3.x; s7 += f3.y;
    }
    float* q = part2 + (size_t)blockIdx.y * SBO + (size_t)t8 * 8;
    *(float4*)q       = make_float4(s0, s1, s2, s3);
    *(float4*)(q + 4) = make_float4(s4, s5, s6, s7);
}

// ---------------------------------------------------------------------------
// finish_pass: sum (1024/NRED)=32 fp32 partials + squash. grid 80.
// t = (c*128+b)*16+o; o spans 16 consecutive lanes -> shfl reduce for ||s||^2.
// mode 0: vsum = v; 1: vsum += v; 2: out = v.
// ---------------------------------------------------------------------------
__global__ __launch_bounds__(256) void finish_pass(const float* __restrict__ part2,
                                                   float* __restrict__ vsum,   // [C][B][16]
                                                   float* __restrict__ out,    // [B][C][16]
                                                   int mode) {
    const int t = blockIdx.x * 256 + threadIdx.x;
    float sum = 0.f;
#pragma unroll
    for (int s = 0; s < 1024 / NRED; ++s)
        sum += part2[(size_t)s * SBO + t];

    float sq = sum * sum;
    sq += __shfl_xor(sq, 1);
    sq += __shfl_xor(sq, 2);
    sq += __shfl_xor(sq, 4);
    sq += __shfl_xor(sq, 8);
    const float scale = sq / ((1.0f + sq) * sqrtf(sq + 1e-8f));
    const float v = scale * sum;

    if (mode == 0) {
        vsum[t] = v;
    } else if (mode == 1) {
        vsum[t] += v;
    } else {
        const int o = t & 15, b = (t >> 4) & 127, c = t >> 11;
        out[((size_t)b * C_ + c) * O_ + o] = v;
    }
}

extern "C" void kernel_launch(void* const* d_in, const int* in_sizes, int n_in,
                              void* d_out, int out_size, void* d_ws, size_t ws_size,
                              hipStream_t stream) {
    const float* x = (const float*)d_in[0];   // [B,R,8]
    const float* w = (const float*)d_in[1];   // [C,R,8,16]
    float* out = (float*)d_out;               // [B,C,16]

    __half* part = (__half*)d_ws;                         // 1024*20480 fp16 = 41.9 MB
    float* part2 = (float*)(part + (size_t)1024 * SBO);   // 32*20480 fp32 = 2.6 MB
    float* vsum  = part2 + (size_t)32 * SBO;              // 20480 f ([C][B][16])

    const dim3 fgrid(R_ / 8);        // 1024
    const dim3 rgrid(10, 1024 / NRED); // (10,32) = 320 blocks
    const dim3 ggrid(80);

    // iteration 0 (uniform cij; vsum not read)
    fused_iter<<<fgrid, 256, 0, stream>>>(x, w, vsum, part, 0);
    reduce1<<<rgrid, 256, 0, stream>>>(part, part2);
    finish_pass<<<ggrid, 256, 0, stream>>>(part2, vsum, out, 0);

    // iteration 1
    fused_iter<<<fgrid, 256, 0, stream>>>(x, w, vsum, part, 1);
    reduce1<<<rgrid, 256, 0, stream>>>(part, part2);
    finish_pass<<<ggrid, 256, 0, stream>>>(part2, vsum, out, 1);

    // iteration 2 (final: write out)
    fused_iter<<<fgrid, 256, 0, stream>>>(x, w, vsum, part, 1);
    reduce1<<<rgrid, 256, 0, stream>>>(part, part2);
    finish_pass<<<ggrid, 256, 0, stream>>>(part2, vsum, out, 2);
}

// Round 5
// 282.114 us; speedup vs baseline: 1.2418x; 1.2418x over previous
//
#include <hip/hip_runtime.h>
#include <hip/hip_fp16.h>
#include <math.h>

#define B_ 128
#define C_ 10
#define R_ 8192
#define I_ 8
#define O_ 16

typedef __attribute__((ext_vector_type(8))) _Float16 half8;
typedef __attribute__((ext_vector_type(16))) float f32x16;

#define WROW 64            // uints per W row: 16 o * 4
#define WZERO 80           // zero-row index (block-diagonal A trick)
#define SBO (C_ * B_ * O_) // 20480
#define NRED 32            // slots summed per reduce1 block

__device__ __forceinline__ unsigned pk2(float a, float b) {
    __half2 h = __floats2half2_rn(a, b);
    return *(unsigned*)&h;
}

// ---------------------------------------------------------------------------
// fused_iter: one routing iteration. grid 1024 (r-tiles of 8), block 256.
// r3 diagnosis: latency-bound (mode0==mode1), 4 blocks/CU (LDS-capped).
// r2/r4: c-level ILP spills -> single-chain body is final.
// This round: TLP instead of ILP. The x tile is NOT staged in LDS anymore --
// each lane loads its 4 c-invariant fragments (2x float4 -> pk2, bit-identical
// fp16) straight from global. LDS 36.5 -> 20.7 KB => 7 blocks/CU (28 waves),
// and the x-stage write bank conflicts (r4-confirmed) vanish.
// __launch_bounds__(256,6): VGPR cap 85 (r3 body = 60; no spill headroom risk).
// Output: part[slot=blockIdx.x][c][b][o] fp16 partial s sums.
// ---------------------------------------------------------------------------
__global__ __launch_bounds__(256, 6) void fused_iter(const float* __restrict__ x,
                                                     const float* __restrict__ w,
                                                     const float* __restrict__ vsum,  // [C][B][16]
                                                     __half* __restrict__ part,
                                                     int mode) {
    __shared__ unsigned wls[(80 + 1) * WROW];   // 20.25 KB (only W staged)

    const int tid = threadIdx.x;
    const int wave = tid >> 6;
    const int lane = tid & 63;
    const int n = lane & 31;
    const int g = lane >> 5;            // k-half / o-half selector
    const int rp_m = (lane & 31) >> 4;  // r' of this lane's A row
    const int o_m = lane & 15;          // o of this lane's A row
    const int b = wave * 32 + n;        // global batch 0..127
    const int r0 = blockIdx.x * 8;

    // ---- stage W for ALL c fp16: wls[c*8+r][o][4 b32], once ----
#pragma unroll
    for (int k = 0; k < 5; ++k) {
        const int id = k * 256 + tid;           // 0..1279 = (c, r, o)
        const int o = id & 15;
        const int r = (id >> 4) & 7;
        const int c = id >> 7;
        const float* wp = w + ((size_t)(c * R_ + r0 + r) * 8) * 16 + o;
        const float f0 = wp[0],  f1 = wp[16],  f2 = wp[32],  f3 = wp[48];
        const float f4 = wp[64], f5 = wp[80],  f6 = wp[96],  f7 = wp[112];
        *(uint4*)(wls + (c * 8 + r) * WROW + o * 4) =
            make_uint4(pk2(f0, f1), pk2(f2, f3), pk2(f4, f5), pk2(f6, f7));
    }
    if (tid < WROW) wls[WZERO * WROW + tid] = 0u;

    // ---- x fragments straight from global (c-invariant, 16 VGPRs).
    // Issued before the barrier so HBM/L3 latency overlaps the W-stage wait.
    union H8 { uint4 u; half8 h; };
    half8 xbr[4];
#pragma unroll
    for (int rp = 0; rp < 4; ++rp) {
        const int row = 2 * rp + g;
        const float* xp = x + ((size_t)b * R_ + r0 + row) * 8;
        const float4 v0 = *(const float4*)xp;
        const float4 v1 = *(const float4*)(xp + 4);
        H8 t;
        t.u = make_uint4(pk2(v0.x, v0.y), pk2(v0.z, v0.w),
                         pk2(v1.x, v1.y), pk2(v1.z, v1.w));
        xbr[rp] = t.h;
    }

    __syncthreads();

    const int act = (g == rp_m);

    // hoisted zero accumulator: MFMA C operand (D != C), no per-use init
    f32x16 zero16;
#pragma unroll
    for (int j = 0; j < 16; ++j) zero16[j] = 0.f;

    if (mode) {
        // ================= mode 1: softmax-weighted =================
        // ---- phase 2: denominators d[r] = sum_c exp(p[c,r]) ----
        float dinv[4];
        {
            float dacc[4] = {0.f, 0.f, 0.f, 0.f};
#pragma unroll 1
            for (int c = 0; c < C_; ++c) {
                const float4* vp = (const float4*)(vsum + ((size_t)c * B_ + b) * O_ + 4 * g);
                const float4 va = vp[0];   // o = 4g..4g+3
                const float4 vb = vp[2];   // o = 8+4g..
#pragma unroll
                for (int rp = 0; rp < 4; ++rp) {
                    const int woff = act ? ((c * 8 + 2 * rp + g) * WROW + o_m * 4)
                                         : (WZERO * WROW);
                    const half8 a = *(const half8*)(wls + woff);
                    const f32x16 u = __builtin_amdgcn_mfma_f32_32x32x16_f16(a, xbr[rp], zero16, 0, 0, 0);
                    const float p0 = u[0] * va.x + u[1] * va.y + u[2] * va.z + u[3] * va.w
                                   + u[4] * vb.x + u[5] * vb.y + u[6] * vb.z + u[7] * vb.w;
                    const float p1 = u[8] * va.x + u[9] * va.y + u[10] * va.z + u[11] * va.w
                                   + u[12] * vb.x + u[13] * vb.y + u[14] * vb.z + u[15] * vb.w;
                    const float send = g ? p0 : p1;
                    const float recv = __shfl_xor(send, 32);
                    const float pg = (g ? p1 : p0) + recv;
                    dacc[rp] += __expf(pg);
                }
            }
#pragma unroll
            for (int rp = 0; rp < 4; ++rp) dinv[rp] = 1.0f / dacc[rp];
        }

        // ---- phase 3: weighted accumulation ----
#pragma unroll 1
        for (int c = 0; c < C_; ++c) {
            const float4* vp = (const float4*)(vsum + ((size_t)c * B_ + b) * O_ + 4 * g);
            const float4 va = vp[0];
            const float4 vb = vp[2];
            f32x16 acc;
#pragma unroll
            for (int rp = 0; rp < 4; ++rp) {
                const int woff = act ? ((c * 8 + 2 * rp + g) * WROW + o_m * 4)
                                     : (WZERO * WROW);
                const half8 a = *(const half8*)(wls + woff);
                const f32x16 u = __builtin_amdgcn_mfma_f32_32x32x16_f16(a, xbr[rp], zero16, 0, 0, 0);
                const float p0 = u[0] * va.x + u[1] * va.y + u[2] * va.z + u[3] * va.w
                               + u[4] * vb.x + u[5] * vb.y + u[6] * vb.z + u[7] * vb.w;
                const float p1 = u[8] * va.x + u[9] * va.y + u[10] * va.z + u[11] * va.w
                               + u[12] * vb.x + u[13] * vb.y + u[14] * vb.z + u[15] * vb.w;
                const float send = g ? p0 : p1;
                const float recv = __shfl_xor(send, 32);
                const float pg = (g ? p1 : p0) + recv;
                const float w_own = __expf(pg) * dinv[rp];     // weight for r = 2rp+g
                const float w_oth = __shfl_xor(w_own, 32);     // partner's (r = 2rp+(1-g))
                const float c0 = g ? w_oth : w_own;            // r' = 0 rows (u[0..7])
                const float c1 = g ? w_own : w_oth;            // r' = 1 rows (u[8..15])
                if (rp == 0) {
#pragma unroll
                    for (int j = 0; j < 8; ++j)  acc[j] = c0 * u[j];
#pragma unroll
                    for (int j = 8; j < 16; ++j) acc[j] = c1 * u[j];
                } else {
#pragma unroll
                    for (int j = 0; j < 8; ++j)  acc[j] += c0 * u[j];
#pragma unroll
                    for (int j = 8; j < 16; ++j) acc[j] += c1 * u[j];
                }
            }
            const float f0 = acc[0] + acc[8],  f1 = acc[1] + acc[9];
            const float f2 = acc[2] + acc[10], f3 = acc[3] + acc[11];
            const float f4 = acc[4] + acc[12], f5 = acc[5] + acc[13];
            const float f6 = acc[6] + acc[14], f7 = acc[7] + acc[15];
            __half* pp = part + (((size_t)blockIdx.x * C_ + c) * B_ + b) * O_;
            *(uint2*)(pp + 4 * g)     = make_uint2(pk2(f0, f1), pk2(f2, f3));
            *(uint2*)(pp + 8 + 4 * g) = make_uint2(pk2(f4, f5), pk2(f6, f7));
        }
    } else {
        // ================= mode 0: uniform weights 0.1 =================
#pragma unroll 1
        for (int c = 0; c < C_; ++c) {
            f32x16 acc = zero16;
#pragma unroll
            for (int rp = 0; rp < 4; ++rp) {
                const int woff = act ? ((c * 8 + 2 * rp + g) * WROW + o_m * 4)
                                     : (WZERO * WROW);
                const half8 a = *(const half8*)(wls + woff);
                acc = __builtin_amdgcn_mfma_f32_32x32x16_f16(a, xbr[rp], acc, 0, 0, 0);
            }
            const float f0 = (acc[0] + acc[8])  * 0.1f, f1 = (acc[1] + acc[9])  * 0.1f;
            const float f2 = (acc[2] + acc[10]) * 0.1f, f3 = (acc[3] + acc[11]) * 0.1f;
            const float f4 = (acc[4] + acc[12]) * 0.1f, f5 = (acc[5] + acc[13]) * 0.1f;
            const float f6 = (acc[6] + acc[14]) * 0.1f, f7 = (acc[7] + acc[15]) * 0.1f;
            __half* pp = part + (((size_t)blockIdx.x * C_ + c) * B_ + b) * O_;
            *(uint2*)(pp + 4 * g)     = make_uint2(pk2(f0, f1), pk2(f2, f3));
            *(uint2*)(pp + 8 + 4 * g) = make_uint2(pk2(f4, f5), pk2(f6, f7));
        }
    }
}

// ---------------------------------------------------------------------------
// reduce1: part2[by][..] = sum of NRED slot-partials. grid (10, 1024/NRED) =
// (10,32) -> 320 blocks. Each thread owns 8 consecutive halfs, uint4 loads.
// ---------------------------------------------------------------------------
__global__ __launch_bounds__(256) void reduce1(const __half* __restrict__ part,
                                               float* __restrict__ part2) {
    const int t8 = blockIdx.x * 256 + threadIdx.x;      // 0..2559
    const __half* p = part + (size_t)(blockIdx.y * NRED) * SBO + (size_t)t8 * 8;
    float s0 = 0.f, s1 = 0.f, s2 = 0.f, s3 = 0.f;
    float s4 = 0.f, s5 = 0.f, s6 = 0.f, s7 = 0.f;
#pragma unroll 8
    for (int s = 0; s < NRED; ++s) {
        const uint4 v = *(const uint4*)(p + (size_t)s * SBO);
        const float2 f0 = __half22float2(*(const __half2*)&v.x);
        const float2 f1 = __half22float2(*(const __half2*)&v.y);
        const float2 f2 = __half22float2(*(const __half2*)&v.z);
        const float2 f3 = __half22float2(*(const __half2*)&v.w);
        s0 += f0.x; s1 += f0.y; s2 += f1.x; s3 += f1.y;
        s4 += f2.x; s5 += f2.y; s6 += f3.x; s7 += f3.y;
    }
    float* q = part2 + (size_t)blockIdx.y * SBO + (size_t)t8 * 8;
    *(float4*)q       = make_float4(s0, s1, s2, s3);
    *(float4*)(q + 4) = make_float4(s4, s5, s6, s7);
}

// ---------------------------------------------------------------------------
// finish_pass: sum (1024/NRED)=32 fp32 partials + squash. grid 80.
// t = (c*128+b)*16+o; o spans 16 consecutive lanes -> shfl reduce for ||s||^2.
// mode 0: vsum = v; 1: vsum += v; 2: out = v.
// ---------------------------------------------------------------------------
__global__ __launch_bounds__(256) void finish_pass(const float* __restrict__ part2,
                                                   float* __restrict__ vsum,   // [C][B][16]
                                                   float* __restrict__ out,    // [B][C][16]
                                                   int mode) {
    const int t = blockIdx.x * 256 + threadIdx.x;
    float sum = 0.f;
#pragma unroll
    for (int s = 0; s < 1024 / NRED; ++s)
        sum += part2[(size_t)s * SBO + t];

    float sq = sum * sum;
    sq += __shfl_xor(sq, 1);
    sq += __shfl_xor(sq, 2);
    sq += __shfl_xor(sq, 4);
    sq += __shfl_xor(sq, 8);
    const float scale = sq / ((1.0f + sq) * sqrtf(sq + 1e-8f));
    const float v = scale * sum;

    if (mode == 0) {
        vsum[t] = v;
    } else if (mode == 1) {
        vsum[t] += v;
    } else {
        const int o = t & 15, b = (t >> 4) & 127, c = t >> 11;
        out[((size_t)b * C_ + c) * O_ + o] = v;
    }
}

extern "C" void kernel_launch(void* const* d_in, const int* in_sizes, int n_in,
                              void* d_out, int out_size, void* d_ws, size_t ws_size,
                              hipStream_t stream) {
    const float* x = (const float*)d_in[0];   // [B,R,8]
    const float* w = (const float*)d_in[1];   // [C,R,8,16]
    float* out = (float*)d_out;               // [B,C,16]

    __half* part = (__half*)d_ws;                         // 1024*20480 fp16 = 41.9 MB
    float* part2 = (float*)(part + (size_t)1024 * SBO);   // 32*20480 fp32 = 2.6 MB
    float* vsum  = part2 + (size_t)32 * SBO;              // 20480 f ([C][B][16])

    const dim3 fgrid(R_ / 8);          // 1024
    const dim3 rgrid(10, 1024 / NRED); // (10,32) = 320 blocks
    const dim3 ggrid(80);

    // iteration 0 (uniform cij; vsum not read)
    fused_iter<<<fgrid, 256, 0, stream>>>(x, w, vsum, part, 0);
    reduce1<<<rgrid, 256, 0, stream>>>(part, part2);
    finish_pass<<<ggrid, 256, 0, stream>>>(part2, vsum, out, 0);

    // iteration 1
    fused_iter<<<fgrid, 256, 0, stream>>>(x, w, vsum, part, 1);
    reduce1<<<rgrid, 256, 0, stream>>>(part, part2);
    finish_pass<<<ggrid, 256, 0, stream>>>(part2, vsum, out, 1);

    // iteration 2 (final: write out)
    fused_iter<<<fgrid, 256, 0, stream>>>(x, w, vsum, part, 1);
    reduce1<<<rgrid, 256, 0, stream>>>(part, part2);
    finish_pass<<<ggrid, 256, 0, stream>>>(part2, vsum, out, 2);
}

// Round 6
// 246.685 us; speedup vs baseline: 1.4202x; 1.1436x over previous
//
#include <hip/hip_runtime.h>
#include <hip/hip_fp16.h>
#include <math.h>

#define B_ 128
#define C_ 10
#define R_ 8192
#define I_ 8
#define O_ 16

typedef __attribute__((ext_vector_type(8))) _Float16 half8;
typedef __attribute__((ext_vector_type(16))) float f32x16;

#define WROW 64            // uints per W row: 16 o * 4
#define WZERO 80           // zero-row index (block-diagonal A trick)
#define SBO (C_ * B_ * O_) // 20480
#define NRED 32            // slots summed per reduce1 block

__device__ __forceinline__ unsigned pk2(float a, float b) {
    __half2 h = __floats2half2_rn(a, b);
    return *(unsigned*)&h;
}

// ---------------------------------------------------------------------------
// fused_iter: one routing iteration. grid 1024 (r-tiles of 8), block 256.
// Register-pressure ledger (hard-won):
//   cap128 + x-in-LDS        -> 60 VGPR, clean, 47.5us   (r3)
//   cap128 + dual-c-chain    -> spill (FETCH/WRITE 3x)   (r4)
//   cap84  + x-from-global   -> spill, VGPR forced to 40 (r5)
// This round: x-from-global (LDS 36.5->20.25KB, kills x-stage conflicts +
// 16KB traffic) at __launch_bounds__(256,5): VGPR cap 102. x loads issued in
// TWO batches of 2 rp (4 float4 in flight = 16 VGPR peak, not 32) to keep
// the staging peak under the cap. Math bit-identical to r3.
// Spill tripwire: WRITE_SIZE must stay ~41MB.
// Output: part[slot=blockIdx.x][c][b][o] fp16 partial s sums.
// ---------------------------------------------------------------------------
__global__ __launch_bounds__(256, 5) void fused_iter(const float* __restrict__ x,
                                                     const float* __restrict__ w,
                                                     const float* __restrict__ vsum,  // [C][B][16]
                                                     __half* __restrict__ part,
                                                     int mode) {
    __shared__ unsigned wls[(80 + 1) * WROW];   // 20.25 KB (only W staged)

    const int tid = threadIdx.x;
    const int wave = tid >> 6;
    const int lane = tid & 63;
    const int n = lane & 31;
    const int g = lane >> 5;            // k-half / o-half selector
    const int rp_m = (lane & 31) >> 4;  // r' of this lane's A row
    const int o_m = lane & 15;          // o of this lane's A row
    const int b = wave * 32 + n;        // global batch 0..127
    const int r0 = blockIdx.x * 8;

    // ---- stage W for ALL c fp16: wls[c*8+r][o][4 b32], once ----
#pragma unroll
    for (int k = 0; k < 5; ++k) {
        const int id = k * 256 + tid;           // 0..1279 = (c, r, o)
        const int o = id & 15;
        const int r = (id >> 4) & 7;
        const int c = id >> 7;
        const float* wp = w + ((size_t)(c * R_ + r0 + r) * 8) * 16 + o;
        const float f0 = wp[0],  f1 = wp[16],  f2 = wp[32],  f3 = wp[48];
        const float f4 = wp[64], f5 = wp[80],  f6 = wp[96],  f7 = wp[112];
        *(uint4*)(wls + (c * 8 + r) * WROW + o * 4) =
            make_uint4(pk2(f0, f1), pk2(f2, f3), pk2(f4, f5), pk2(f6, f7));
    }
    if (tid < WROW) wls[WZERO * WROW + tid] = 0u;

    // ---- x fragments straight from global (c-invariant, 16 VGPRs live).
    // Two batches of 2 rp: max 4 float4 in flight -> staging peak ~16 regs.
    union H8 { uint4 u; half8 h; };
    half8 xbr[4];
#pragma unroll
    for (int h = 0; h < 2; ++h) {
        float4 v0a, v1a, v0b, v1b;
        {
            const int row = 2 * (2 * h + 0) + g;
            const float* xp = x + ((size_t)b * R_ + r0 + row) * 8;
            v0a = *(const float4*)xp;
            v1a = *(const float4*)(xp + 4);
        }
        {
            const int row = 2 * (2 * h + 1) + g;
            const float* xp = x + ((size_t)b * R_ + r0 + row) * 8;
            v0b = *(const float4*)xp;
            v1b = *(const float4*)(xp + 4);
        }
        H8 ta, tb;
        ta.u = make_uint4(pk2(v0a.x, v0a.y), pk2(v0a.z, v0a.w),
                          pk2(v1a.x, v1a.y), pk2(v1a.z, v1a.w));
        tb.u = make_uint4(pk2(v0b.x, v0b.y), pk2(v0b.z, v0b.w),
                          pk2(v1b.x, v1b.y), pk2(v1b.z, v1b.w));
        xbr[2 * h + 0] = ta.h;
        xbr[2 * h + 1] = tb.h;
    }

    __syncthreads();

    const int act = (g == rp_m);

    // hoisted zero accumulator: MFMA C operand (D != C), no per-use init
    f32x16 zero16;
#pragma unroll
    for (int j = 0; j < 16; ++j) zero16[j] = 0.f;

    if (mode) {
        // ================= mode 1: softmax-weighted =================
        // ---- phase 2: denominators d[r] = sum_c exp(p[c,r]) ----
        float dinv[4];
        {
            float dacc[4] = {0.f, 0.f, 0.f, 0.f};
#pragma unroll 1
            for (int c = 0; c < C_; ++c) {
                const float4* vp = (const float4*)(vsum + ((size_t)c * B_ + b) * O_ + 4 * g);
                const float4 va = vp[0];   // o = 4g..4g+3
                const float4 vb = vp[2];   // o = 8+4g..
#pragma unroll
                for (int rp = 0; rp < 4; ++rp) {
                    const int woff = act ? ((c * 8 + 2 * rp + g) * WROW + o_m * 4)
                                         : (WZERO * WROW);
                    const half8 a = *(const half8*)(wls + woff);
                    const f32x16 u = __builtin_amdgcn_mfma_f32_32x32x16_f16(a, xbr[rp], zero16, 0, 0, 0);
                    const float p0 = u[0] * va.x + u[1] * va.y + u[2] * va.z + u[3] * va.w
                                   + u[4] * vb.x + u[5] * vb.y + u[6] * vb.z + u[7] * vb.w;
                    const float p1 = u[8] * va.x + u[9] * va.y + u[10] * va.z + u[11] * va.w
                                   + u[12] * vb.x + u[13] * vb.y + u[14] * vb.z + u[15] * vb.w;
                    const float send = g ? p0 : p1;
                    const float recv = __shfl_xor(send, 32);
                    const float pg = (g ? p1 : p0) + recv;
                    dacc[rp] += __expf(pg);
                }
            }
#pragma unroll
            for (int rp = 0; rp < 4; ++rp) dinv[rp] = 1.0f / dacc[rp];
        }

        // ---- phase 3: weighted accumulation ----
#pragma unroll 1
        for (int c = 0; c < C_; ++c) {
            const float4* vp = (const float4*)(vsum + ((size_t)c * B_ + b) * O_ + 4 * g);
            const float4 va = vp[0];
            const float4 vb = vp[2];
            f32x16 acc;
#pragma unroll
            for (int rp = 0; rp < 4; ++rp) {
                const int woff = act ? ((c * 8 + 2 * rp + g) * WROW + o_m * 4)
                                     : (WZERO * WROW);
                const half8 a = *(const half8*)(wls + woff);
                const f32x16 u = __builtin_amdgcn_mfma_f32_32x32x16_f16(a, xbr[rp], zero16, 0, 0, 0);
                const float p0 = u[0] * va.x + u[1] * va.y + u[2] * va.z + u[3] * va.w
                               + u[4] * vb.x + u[5] * vb.y + u[6] * vb.z + u[7] * vb.w;
                const float p1 = u[8] * va.x + u[9] * va.y + u[10] * va.z + u[11] * va.w
                               + u[12] * vb.x + u[13] * vb.y + u[14] * vb.z + u[15] * vb.w;
                const float send = g ? p0 : p1;
                const float recv = __shfl_xor(send, 32);
                const float pg = (g ? p1 : p0) + recv;
                const float w_own = __expf(pg) * dinv[rp];     // weight for r = 2rp+g
                const float w_oth = __shfl_xor(w_own, 32);     // partner's (r = 2rp+(1-g))
                const float c0 = g ? w_oth : w_own;            // r' = 0 rows (u[0..7])
                const float c1 = g ? w_own : w_oth;            // r' = 1 rows (u[8..15])
                if (rp == 0) {
#pragma unroll
                    for (int j = 0; j < 8; ++j)  acc[j] = c0 * u[j];
#pragma unroll
                    for (int j = 8; j < 16; ++j) acc[j] = c1 * u[j];
                } else {
#pragma unroll
                    for (int j = 0; j < 8; ++j)  acc[j] += c0 * u[j];
#pragma unroll
                    for (int j = 8; j < 16; ++j) acc[j] += c1 * u[j];
                }
            }
            const float f0 = acc[0] + acc[8],  f1 = acc[1] + acc[9];
            const float f2 = acc[2] + acc[10], f3 = acc[3] + acc[11];
            const float f4 = acc[4] + acc[12], f5 = acc[5] + acc[13];
            const float f6 = acc[6] + acc[14], f7 = acc[7] + acc[15];
            __half* pp = part + (((size_t)blockIdx.x * C_ + c) * B_ + b) * O_;
            *(uint2*)(pp + 4 * g)     = make_uint2(pk2(f0, f1), pk2(f2, f3));
            *(uint2*)(pp + 8 + 4 * g) = make_uint2(pk2(f4, f5), pk2(f6, f7));
        }
    } else {
        // ================= mode 0: uniform weights 0.1 =================
#pragma unroll 1
        for (int c = 0; c < C_; ++c) {
            f32x16 acc = zero16;
#pragma unroll
            for (int rp = 0; rp < 4; ++rp) {
                const int woff = act ? ((c * 8 + 2 * rp + g) * WROW + o_m * 4)
                                     : (WZERO * WROW);
                const half8 a = *(const half8*)(wls + woff);
                acc = __builtin_amdgcn_mfma_f32_32x32x16_f16(a, xbr[rp], acc, 0, 0, 0);
            }
            const float f0 = (acc[0] + acc[8])  * 0.1f, f1 = (acc[1] + acc[9])  * 0.1f;
            const float f2 = (acc[2] + acc[10]) * 0.1f, f3 = (acc[3] + acc[11]) * 0.1f;
            const float f4 = (acc[4] + acc[12]) * 0.1f, f5 = (acc[5] + acc[13]) * 0.1f;
            const float f6 = (acc[6] + acc[14]) * 0.1f, f7 = (acc[7] + acc[15]) * 0.1f;
            __half* pp = part + (((size_t)blockIdx.x * C_ + c) * B_ + b) * O_;
            *(uint2*)(pp + 4 * g)     = make_uint2(pk2(f0, f1), pk2(f2, f3));
            *(uint2*)(pp + 8 + 4 * g) = make_uint2(pk2(f4, f5), pk2(f6, f7));
        }
    }
}

// ---------------------------------------------------------------------------
// reduce1: part2[by][..] = sum of NRED slot-partials. grid (10, 1024/NRED) =
// (10,32) -> 320 blocks. Each thread owns 8 consecutive halfs, uint4 loads.
// ---------------------------------------------------------------------------
__global__ __launch_bounds__(256) void reduce1(const __half* __restrict__ part,
                                               float* __restrict__ part2) {
    const int t8 = blockIdx.x * 256 + threadIdx.x;      // 0..2559
    const __half* p = part + (size_t)(blockIdx.y * NRED) * SBO + (size_t)t8 * 8;
    float s0 = 0.f, s1 = 0.f, s2 = 0.f, s3 = 0.f;
    float s4 = 0.f, s5 = 0.f, s6 = 0.f, s7 = 0.f;
#pragma unroll 8
    for (int s = 0; s < NRED; ++s) {
        const uint4 v = *(const uint4*)(p + (size_t)s * SBO);
        const float2 f0 = __half22float2(*(const __half2*)&v.x);
        const float2 f1 = __half22float2(*(const __half2*)&v.y);
        const float2 f2 = __half22float2(*(const __half2*)&v.z);
        const float2 f3 = __half22float2(*(const __half2*)&v.w);
        s0 += f0.x; s1 += f0.y; s2 += f1.x; s3 += f1.y;
        s4 += f2.x; s5 += f2.y; s6 += f3.x; s7 += f3.y;
    }
    float* q = part2 + (size_t)blockIdx.y * SBO + (size_t)t8 * 8;
    *(float4*)q       = make_float4(s0, s1, s2, s3);
    *(float4*)(q + 4) = make_float4(s4, s5, s6, s7);
}

// ---------------------------------------------------------------------------
// finish_pass: sum (1024/NRED)=32 fp32 partials + squash. grid 80.
// t = (c*128+b)*16+o; o spans 16 consecutive lanes -> shfl reduce for ||s||^2.
// mode 0: vsum = v; 1: vsum += v; 2: out = v.
// ---------------------------------------------------------------------------
__global__ __launch_bounds__(256) void finish_pass(const float* __restrict__ part2,
                                                   float* __restrict__ vsum,   // [C][B][16]
                                                   float* __restrict__ out,    // [B][C][16]
                                                   int mode) {
    const int t = blockIdx.x * 256 + threadIdx.x;
    float sum = 0.f;
#pragma unroll
    for (int s = 0; s < 1024 / NRED; ++s)
        sum += part2[(size_t)s * SBO + t];

    float sq = sum * sum;
    sq += __shfl_xor(sq, 1);
    sq += __shfl_xor(sq, 2);
    sq += __shfl_xor(sq, 4);
    sq += __shfl_xor(sq, 8);
    const float scale = sq / ((1.0f + sq) * sqrtf(sq + 1e-8f));
    const float v = scale * sum;

    if (mode == 0) {
        vsum[t] = v;
    } else if (mode == 1) {
        vsum[t] += v;
    } else {
        const int o = t & 15, b = (t >> 4) & 127, c = t >> 11;
        out[((size_t)b * C_ + c) * O_ + o] = v;
    }
}

extern "C" void kernel_launch(void* const* d_in, const int* in_sizes, int n_in,
                              void* d_out, int out_size, void* d_ws, size_t ws_size,
                              hipStream_t stream) {
    const float* x = (const float*)d_in[0];   // [B,R,8]
    const float* w = (const float*)d_in[1];   // [C,R,8,16]
    float* out = (float*)d_out;               // [B,C,16]

    __half* part = (__half*)d_ws;                         // 1024*20480 fp16 = 41.9 MB
    float* part2 = (float*)(part + (size_t)1024 * SBO);   // 32*20480 fp32 = 2.6 MB
    float* vsum  = part2 + (size_t)32 * SBO;              // 20480 f ([C][B][16])

    const dim3 fgrid(R_ / 8);          // 1024
    const dim3 rgrid(10, 1024 / NRED); // (10,32) = 320 blocks
    const dim3 ggrid(80);

    // iteration 0 (uniform cij; vsum not read)
    fused_iter<<<fgrid, 256, 0, stream>>>(x, w, vsum, part, 0);
    reduce1<<<rgrid, 256, 0, stream>>>(part, part2);
    finish_pass<<<ggrid, 256, 0, stream>>>(part2, vsum, out, 0);

    // iteration 1
    fused_iter<<<fgrid, 256, 0, stream>>>(x, w, vsum, part, 1);
    reduce1<<<rgrid, 256, 0, stream>>>(part, part2);
    finish_pass<<<ggrid, 256, 0, stream>>>(part2, vsum, out, 1);

    // iteration 2 (final: write out)
    fused_iter<<<fgrid, 256, 0, stream>>>(x, w, vsum, part, 1);
    reduce1<<<rgrid, 256, 0, stream>>>(part, part2);
    finish_pass<<<ggrid, 256, 0, stream>>>(part2, vsum, out, 2);
}

// Round 7
// 232.970 us; speedup vs baseline: 1.5038x; 1.0589x over previous
//
#include <hip/hip_runtime.h>
#include <hip/hip_fp16.h>
#include <math.h>

#define B_ 128
#define C_ 10
#define R_ 8192
#define I_ 8
#define O_ 16

typedef __attribute__((ext_vector_type(8))) _Float16 half8;
typedef __attribute__((ext_vector_type(16))) float f32x16;

#define WROW 64            // uints per W row: 16 o * 4
#define WZERO 80           // zero-row index (block-diagonal A trick)
#define SBO (C_ * B_ * O_) // 20480
#define NRED 32            // slots summed per reduce1 block

__device__ __forceinline__ unsigned pk2(float a, float b) {
    __half2 h = __floats2half2_rn(a, b);
    return *(unsigned*)&h;
}

// ---------------------------------------------------------------------------
// fused_iter: one routing iteration. grid 1024 (r-tiles of 8), block 256.
// Register ledger (rocprof VGPR_Count reads ~= true/2):
//   r3 cap128 x-in-LDS      : rep 60 (~120 true), clean, 47.5us -> VGPR-limited 4 blk/CU
//   r4 cap128 dual-chain    : spill (demand ~160)
//   r5 cap84  x-from-global : spill (demand ~110 > 84)
//   r6 cap102 x-from-global : mild spill (demand ~110 > 102), 62us
// This round: cut TRUE demand ~24 regs so ~96 fits cap 102 -> 5 blk/CU clean:
//   - acc 16 -> 8 floats: fold r'-halves at accumulate time
//     (acc8[j] += c0*u[j] + c1*u[j+8]; fp32 reassoc, ~ulp noise).
//   - no hoisted zero16: u zero-init in-loop (allocator rematerializes).
// Spill tripwire: WRITE_SIZE must be 40960 KB exactly.
// Output: part[slot=blockIdx.x][c][b][o] fp16 partial s sums.
// ---------------------------------------------------------------------------
__global__ __launch_bounds__(256, 5) void fused_iter(const float* __restrict__ x,
                                                     const float* __restrict__ w,
                                                     const float* __restrict__ vsum,  // [C][B][16]
                                                     __half* __restrict__ part,
                                                     int mode) {
    __shared__ unsigned wls[(80 + 1) * WROW];   // 20.25 KB (only W staged)

    const int tid = threadIdx.x;
    const int wave = tid >> 6;
    const int lane = tid & 63;
    const int n = lane & 31;
    const int g = lane >> 5;            // k-half / o-half selector
    const int rp_m = (lane & 31) >> 4;  // r' of this lane's A row
    const int o_m = lane & 15;          // o of this lane's A row
    const int b = wave * 32 + n;        // global batch 0..127
    const int r0 = blockIdx.x * 8;

    // ---- stage W for ALL c fp16: wls[c*8+r][o][4 b32], once ----
#pragma unroll
    for (int k = 0; k < 5; ++k) {
        const int id = k * 256 + tid;           // 0..1279 = (c, r, o)
        const int o = id & 15;
        const int r = (id >> 4) & 7;
        const int c = id >> 7;
        const float* wp = w + ((size_t)(c * R_ + r0 + r) * 8) * 16 + o;
        const float f0 = wp[0],  f1 = wp[16],  f2 = wp[32],  f3 = wp[48];
        const float f4 = wp[64], f5 = wp[80],  f6 = wp[96],  f7 = wp[112];
        *(uint4*)(wls + (c * 8 + r) * WROW + o * 4) =
            make_uint4(pk2(f0, f1), pk2(f2, f3), pk2(f4, f5), pk2(f6, f7));
    }
    if (tid < WROW) wls[WZERO * WROW + tid] = 0u;

    // ---- x fragments straight from global (c-invariant, 16 VGPRs live) ----
    union H8 { uint4 u; half8 h; };
    half8 xbr[4];
#pragma unroll
    for (int rp = 0; rp < 4; ++rp) {
        const int row = 2 * rp + g;
        const float* xp = x + ((size_t)b * R_ + r0 + row) * 8;
        const float4 v0 = *(const float4*)xp;
        const float4 v1 = *(const float4*)(xp + 4);
        H8 t;
        t.u = make_uint4(pk2(v0.x, v0.y), pk2(v0.z, v0.w),
                         pk2(v1.x, v1.y), pk2(v1.z, v1.w));
        xbr[rp] = t.h;
    }

    __syncthreads();

    const int act = (g == rp_m);

    if (mode) {
        // ================= mode 1: softmax-weighted =================
        // ---- phase 2: denominators d[r] = sum_c exp(p[c,r]) ----
        float dinv[4];
        {
            float dacc[4] = {0.f, 0.f, 0.f, 0.f};
#pragma unroll 1
            for (int c = 0; c < C_; ++c) {
                const float4* vp = (const float4*)(vsum + ((size_t)c * B_ + b) * O_ + 4 * g);
                const float4 va = vp[0];   // o = 4g..4g+3
                const float4 vb = vp[2];   // o = 8+4g..
#pragma unroll
                for (int rp = 0; rp < 4; ++rp) {
                    const int woff = act ? ((c * 8 + 2 * rp + g) * WROW + o_m * 4)
                                         : (WZERO * WROW);
                    const half8 a = *(const half8*)(wls + woff);
                    f32x16 u;
#pragma unroll
                    for (int j = 0; j < 16; ++j) u[j] = 0.f;
                    u = __builtin_amdgcn_mfma_f32_32x32x16_f16(a, xbr[rp], u, 0, 0, 0);
                    const float p0 = u[0] * va.x + u[1] * va.y + u[2] * va.z + u[3] * va.w
                                   + u[4] * vb.x + u[5] * vb.y + u[6] * vb.z + u[7] * vb.w;
                    const float p1 = u[8] * va.x + u[9] * va.y + u[10] * va.z + u[11] * va.w
                                   + u[12] * vb.x + u[13] * vb.y + u[14] * vb.z + u[15] * vb.w;
                    const float send = g ? p0 : p1;
                    const float recv = __shfl_xor(send, 32);
                    const float pg = (g ? p1 : p0) + recv;
                    dacc[rp] += __expf(pg);
                }
            }
#pragma unroll
            for (int rp = 0; rp < 4; ++rp) dinv[rp] = 1.0f / dacc[rp];
        }

        // ---- phase 3: weighted accumulation (8-wide acc) ----
#pragma unroll 1
        for (int c = 0; c < C_; ++c) {
            const float4* vp = (const float4*)(vsum + ((size_t)c * B_ + b) * O_ + 4 * g);
            const float4 va = vp[0];
            const float4 vb = vp[2];
            float acc[8];
#pragma unroll
            for (int rp = 0; rp < 4; ++rp) {
                const int woff = act ? ((c * 8 + 2 * rp + g) * WROW + o_m * 4)
                                     : (WZERO * WROW);
                const half8 a = *(const half8*)(wls + woff);
                f32x16 u;
#pragma unroll
                for (int j = 0; j < 16; ++j) u[j] = 0.f;
                u = __builtin_amdgcn_mfma_f32_32x32x16_f16(a, xbr[rp], u, 0, 0, 0);
                const float p0 = u[0] * va.x + u[1] * va.y + u[2] * va.z + u[3] * va.w
                               + u[4] * vb.x + u[5] * vb.y + u[6] * vb.z + u[7] * vb.w;
                const float p1 = u[8] * va.x + u[9] * va.y + u[10] * va.z + u[11] * va.w
                               + u[12] * vb.x + u[13] * vb.y + u[14] * vb.z + u[15] * vb.w;
                const float send = g ? p0 : p1;
                const float recv = __shfl_xor(send, 32);
                const float pg = (g ? p1 : p0) + recv;
                const float w_own = __expf(pg) * dinv[rp];     // weight for r = 2rp+g
                const float w_oth = __shfl_xor(w_own, 32);     // partner's (r = 2rp+(1-g))
                const float c0 = g ? w_oth : w_own;            // r' = 0 rows (u[0..7])
                const float c1 = g ? w_own : w_oth;            // r' = 1 rows (u[8..15])
                if (rp == 0) {
#pragma unroll
                    for (int j = 0; j < 8; ++j) acc[j] = c0 * u[j] + c1 * u[j + 8];
                } else {
#pragma unroll
                    for (int j = 0; j < 8; ++j) acc[j] += c0 * u[j] + c1 * u[j + 8];
                }
            }
            __half* pp = part + (((size_t)blockIdx.x * C_ + c) * B_ + b) * O_;
            *(uint2*)(pp + 4 * g)     = make_uint2(pk2(acc[0], acc[1]), pk2(acc[2], acc[3]));
            *(uint2*)(pp + 8 + 4 * g) = make_uint2(pk2(acc[4], acc[5]), pk2(acc[6], acc[7]));
        }
    } else {
        // ================= mode 0: uniform weights 0.1 =================
#pragma unroll 1
        for (int c = 0; c < C_; ++c) {
            f32x16 acc;
#pragma unroll
            for (int j = 0; j < 16; ++j) acc[j] = 0.f;
#pragma unroll
            for (int rp = 0; rp < 4; ++rp) {
                const int woff = act ? ((c * 8 + 2 * rp + g) * WROW + o_m * 4)
                                     : (WZERO * WROW);
                const half8 a = *(const half8*)(wls + woff);
                acc = __builtin_amdgcn_mfma_f32_32x32x16_f16(a, xbr[rp], acc, 0, 0, 0);
            }
            const float f0 = (acc[0] + acc[8])  * 0.1f, f1 = (acc[1] + acc[9])  * 0.1f;
            const float f2 = (acc[2] + acc[10]) * 0.1f, f3 = (acc[3] + acc[11]) * 0.1f;
            const float f4 = (acc[4] + acc[12]) * 0.1f, f5 = (acc[5] + acc[13]) * 0.1f;
            const float f6 = (acc[6] + acc[14]) * 0.1f, f7 = (acc[7] + acc[15]) * 0.1f;
            __half* pp = part + (((size_t)blockIdx.x * C_ + c) * B_ + b) * O_;
            *(uint2*)(pp + 4 * g)     = make_uint2(pk2(f0, f1), pk2(f2, f3));
            *(uint2*)(pp + 8 + 4 * g) = make_uint2(pk2(f4, f5), pk2(f6, f7));
        }
    }
}

// ---------------------------------------------------------------------------
// reduce1: part2[by][..] = sum of NRED slot-partials. grid (10, 1024/NRED) =
// (10,32) -> 320 blocks. Each thread owns 8 consecutive halfs, uint4 loads.
// ---------------------------------------------------------------------------
__global__ __launch_bounds__(256) void reduce1(const __half* __restrict__ part,
                                               float* __restrict__ part2) {
    const int t8 = blockIdx.x * 256 + threadIdx.x;      // 0..2559
    const __half* p = part + (size_t)(blockIdx.y * NRED) * SBO + (size_t)t8 * 8;
    float s0 = 0.f, s1 = 0.f, s2 = 0.f, s3 = 0.f;
    float s4 = 0.f, s5 = 0.f, s6 = 0.f, s7 = 0.f;
#pragma unroll 8
    for (int s = 0; s < NRED; ++s) {
        const uint4 v = *(const uint4*)(p + (size_t)s * SBO);
        const float2 f0 = __half22float2(*(const __half2*)&v.x);
        const float2 f1 = __half22float2(*(const __half2*)&v.y);
        const float2 f2 = __half22float2(*(const __half2*)&v.z);
        const float2 f3 = __half22float2(*(const __half2*)&v.w);
        s0 += f0.x; s1 += f0.y; s2 += f1.x; s3 += f1.y;
        s4 += f2.x; s5 += f2.y; s6 += f3.x; s7 += f3.y;
    }
    float* q = part2 + (size_t)blockIdx.y * SBO + (size_t)t8 * 8;
    *(float4*)q       = make_float4(s0, s1, s2, s3);
    *(float4*)(q + 4) = make_float4(s4, s5, s6, s7);
}

// ---------------------------------------------------------------------------
// finish_pass: sum (1024/NRED)=32 fp32 partials + squash. grid 80.
// t = (c*128+b)*16+o; o spans 16 consecutive lanes -> shfl reduce for ||s||^2.
// mode 0: vsum = v; 1: vsum += v; 2: out = v.
// ---------------------------------------------------------------------------
__global__ __launch_bounds__(256) void finish_pass(const float* __restrict__ part2,
                                                   float* __restrict__ vsum,   // [C][B][16]
                                                   float* __restrict__ out,    // [B][C][16]
                                                   int mode) {
    const int t = blockIdx.x * 256 + threadIdx.x;
    float sum = 0.f;
#pragma unroll
    for (int s = 0; s < 1024 / NRED; ++s)
        sum += part2[(size_t)s * SBO + t];

    float sq = sum * sum;
    sq += __shfl_xor(sq, 1);
    sq += __shfl_xor(sq, 2);
    sq += __shfl_xor(sq, 4);
    sq += __shfl_xor(sq, 8);
    const float scale = sq / ((1.0f + sq) * sqrtf(sq + 1e-8f));
    const float v = scale * sum;

    if (mode == 0) {
        vsum[t] = v;
    } else if (mode == 1) {
        vsum[t] += v;
    } else {
        const int o = t & 15, b = (t >> 4) & 127, c = t >> 11;
        out[((size_t)b * C_ + c) * O_ + o] = v;
    }
}

extern "C" void kernel_launch(void* const* d_in, const int* in_sizes, int n_in,
                              void* d_out, int out_size, void* d_ws, size_t ws_size,
                              hipStream_t stream) {
    const float* x = (const float*)d_in[0];   // [B,R,8]
    const float* w = (const float*)d_in[1];   // [C,R,8,16]
    float* out = (float*)d_out;               // [B,C,16]

    __half* part = (__half*)d_ws;                         // 1024*20480 fp16 = 41.9 MB
    float* part2 = (float*)(part + (size_t)1024 * SBO);   // 32*20480 fp32 = 2.6 MB
    float* vsum  = part2 + (size_t)32 * SBO;              // 20480 f ([C][B][16])

    const dim3 fgrid(R_ / 8);          // 1024
    const dim3 rgrid(10, 1024 / NRED); // (10,32) = 320 blocks
    const dim3 ggrid(80);

    // iteration 0 (uniform cij; vsum not read)
    fused_iter<<<fgrid, 256, 0, stream>>>(x, w, vsum, part, 0);
    reduce1<<<rgrid, 256, 0, stream>>>(part, part2);
    finish_pass<<<ggrid, 256, 0, stream>>>(part2, vsum, out, 0);

    // iteration 1
    fused_iter<<<fgrid, 256, 0, stream>>>(x, w, vsum, part, 1);
    reduce1<<<rgrid, 256, 0, stream>>>(part, part2);
    finish_pass<<<ggrid, 256, 0, stream>>>(part2, vsum, out, 1);

    // iteration 2 (final: write out)
    fused_iter<<<fgrid, 256, 0, stream>>>(x, w, vsum, part, 1);
    reduce1<<<rgrid, 256, 0, stream>>>(part, part2);
    finish_pass<<<ggrid, 256, 0, stream>>>(part2, vsum, out, 2);
}